// Round 2
// baseline (398.667 us; speedup 1.0000x reference)
//
#include <hip/hip_runtime.h>

// Fused axial dual-branch attention, fp32, one workgroup per attention index N.
//
// Shapes: z (8,64,128,128) fp32; W_Q,W_K (64,64); out (8,64,128,128).
// Key fact: reshape (1024,128,64)->(4096,16,128) maps head-matrix N=nb*4+q to the
// contiguous 32x64 row block [q*32, q*32+32) of the per-nb GEMM output, row-major.
// So each N is one 32x64 tile: Q1 = A1 @ Wq^T, Q2 = A2 @ Wq^T, V = Vin @ Wk^T,
// scores_b = 0.25 * Qb^T_r Qb_r (Gram of 16x128), softmax rows, ctx_b = V_r @ attn_b,
// out = leaky(ctx1) + leaky(ctx2). V identical across branches (raw reshape).
// Both branches contribute at the SAME flat N (elementwise add of flat (4096,16,128)).

#define WST 68     // padded LDS row stride for weight/A tiles (16B-aligned rows)
#define SST 132    // padded LDS row stride for scores (16B-aligned rows)

__device__ __forceinline__ float lrelu(float x) { return x > 0.f ? x : 0.2f * x; }

// Stage Wq,Wk transposed into uni: uni[ch*WST + o] = W[o*64 + ch]. Region = 2*64*WST floats.
__device__ __forceinline__ void stage_weights(const float* __restrict__ Wq,
                                              const float* __restrict__ Wk,
                                              float* __restrict__ uni, int tid)
{
    float* uq = uni;
    float* uk = uni + 64 * WST;
    #pragma unroll
    for (int i = tid; i < 1024; i += 256) {
        const int o  = i >> 4;
        const int c4 = (i & 15) << 2;
        const float4 wq = *(const float4*)(Wq + o * 64 + c4);
        const float4 wk = *(const float4*)(Wk + o * 64 + c4);
        uq[(c4 + 0) * WST + o] = wq.x; uq[(c4 + 1) * WST + o] = wq.y;
        uq[(c4 + 2) * WST + o] = wq.z; uq[(c4 + 3) * WST + o] = wq.w;
        uk[(c4 + 0) * WST + o] = wk.x; uk[(c4 + 1) * WST + o] = wk.y;
        uk[(c4 + 2) * WST + o] = wk.z; uk[(c4 + 3) * WST + o] = wk.w;
    }
}

// 32x64 = (32x64 sA) @ (64x64 Wt). Thread: 2 rows x 4 cols. Output unpadded stride 64
// (so sO doubles as the 16x128 "reshaped" matrix, row-major, contiguous).
__device__ __forceinline__ void gemm_32x64(const float* __restrict__ sA,
                                           const float* __restrict__ wt,
                                           float* __restrict__ sO, int tid)
{
    const int lp = tid >> 4;      // 0..15 -> rows 2lp, 2lp+1
    const int oq = tid & 15;      // 0..15 -> cols 4oq..4oq+3
    const float* a0p = sA + (2 * lp) * WST;
    const float* a1p = a0p + WST;
    const float* wp  = wt + oq * 4;
    float acc0[4] = {0.f, 0.f, 0.f, 0.f};
    float acc1[4] = {0.f, 0.f, 0.f, 0.f};
    #pragma unroll 16
    for (int ch = 0; ch < 64; ++ch) {
        const float a0 = a0p[ch];
        const float a1 = a1p[ch];
        const float4 w = *(const float4*)(wp + ch * WST);
        acc0[0] = fmaf(a0, w.x, acc0[0]); acc0[1] = fmaf(a0, w.y, acc0[1]);
        acc0[2] = fmaf(a0, w.z, acc0[2]); acc0[3] = fmaf(a0, w.w, acc0[3]);
        acc1[0] = fmaf(a1, w.x, acc1[0]); acc1[1] = fmaf(a1, w.y, acc1[1]);
        acc1[2] = fmaf(a1, w.z, acc1[2]); acc1[3] = fmaf(a1, w.w, acc1[3]);
    }
    *(float4*)(sO + (2 * lp) * 64 + oq * 4)     = make_float4(acc0[0], acc0[1], acc0[2], acc0[3]);
    *(float4*)(sO + (2 * lp + 1) * 64 + oq * 4) = make_float4(acc1[0], acc1[1], acc1[2], acc1[3]);
}

// One branch: Gram(16x128 sQ) -> scores (two 64-row halves through sS), softmax rows,
// ctx[d][t] = sum_s V[d][s]*attn[s][t] accumulated into 8 regs (d = tid>>4, t0=(tid&15)*8).
__device__ __forceinline__ void branch_ctx(const float* __restrict__ sQ,
                                           const float* __restrict__ sV,
                                           float* __restrict__ sS,
                                           float ctx[8], int tid)
{
    const int gi = tid >> 5, gj = tid & 31;        // gram: rows 8gi.., cols 4gj..
    const int sr = tid >> 2, sq4 = tid & 3;        // softmax: row sr, col chunk sq4*32
    const int cd = tid >> 4, ct0 = (tid & 15) * 8; // ctx: d=cd, cols ct0..ct0+7
    #pragma unroll
    for (int k = 0; k < 8; ++k) ctx[k] = 0.f;

    for (int half = 0; half < 2; ++half) {
        const int R = half * 64;
        // ---- Gram: scores[R+8gi+r][4gj+c] = 0.25 * sum_d Qr[d][R+8gi+r]*Qr[d][4gj+c]
        float g[8][4] = {};
        #pragma unroll
        for (int d = 0; d < 16; ++d) {
            const float* qr = sQ + d * 128;
            const float4 ra = *(const float4*)(qr + R + 8 * gi);
            const float4 rb = *(const float4*)(qr + R + 8 * gi + 4);
            const float4 cc = *(const float4*)(qr + 4 * gj);
            const float rr[8] = {ra.x, ra.y, ra.z, ra.w, rb.x, rb.y, rb.z, rb.w};
            #pragma unroll
            for (int r = 0; r < 8; ++r) {
                g[r][0] = fmaf(rr[r], cc.x, g[r][0]);
                g[r][1] = fmaf(rr[r], cc.y, g[r][1]);
                g[r][2] = fmaf(rr[r], cc.z, g[r][2]);
                g[r][3] = fmaf(rr[r], cc.w, g[r][3]);
            }
        }
        __syncthreads();   // prior users of sS (weights / previous half's attn) done
        #pragma unroll
        for (int r = 0; r < 8; ++r) {
            *(float4*)(sS + (8 * gi + r) * SST + 4 * gj) =
                make_float4(0.25f * g[r][0], 0.25f * g[r][1], 0.25f * g[r][2], 0.25f * g[r][3]);
        }
        __syncthreads();
        // ---- softmax over t (row-wise), 4 threads per row
        {
            float* rowp = sS + sr * SST + sq4 * 32;
            float v[32];
            float m = -__builtin_inff();
            #pragma unroll
            for (int k = 0; k < 32; k += 4) {
                const float4 t4 = *(const float4*)(rowp + k);
                v[k] = t4.x; v[k+1] = t4.y; v[k+2] = t4.z; v[k+3] = t4.w;
                m = fmaxf(m, fmaxf(fmaxf(t4.x, t4.y), fmaxf(t4.z, t4.w)));
            }
            m = fmaxf(m, __shfl_xor(m, 1));
            m = fmaxf(m, __shfl_xor(m, 2));
            float ssum = 0.f;
            #pragma unroll
            for (int k = 0; k < 32; ++k) { v[k] = __expf(v[k] - m); ssum += v[k]; }
            ssum += __shfl_xor(ssum, 1);
            ssum += __shfl_xor(ssum, 2);
            const float inv = 1.0f / ssum;
            #pragma unroll
            for (int k = 0; k < 32; k += 4) {
                *(float4*)(rowp + k) =
                    make_float4(v[k] * inv, v[k+1] * inv, v[k+2] * inv, v[k+3] * inv);
            }
        }
        __syncthreads();
        // ---- ctx accumulate over this half's s
        const float* vrow = sV + cd * 128 + R;
        #pragma unroll 8
        for (int s = 0; s < 64; ++s) {
            const float vv = vrow[s];
            const float4 a0 = *(const float4*)(sS + s * SST + ct0);
            const float4 a1 = *(const float4*)(sS + s * SST + ct0 + 4);
            ctx[0] = fmaf(vv, a0.x, ctx[0]); ctx[1] = fmaf(vv, a0.y, ctx[1]);
            ctx[2] = fmaf(vv, a0.z, ctx[2]); ctx[3] = fmaf(vv, a0.w, ctx[3]);
            ctx[4] = fmaf(vv, a1.x, ctx[4]); ctx[5] = fmaf(vv, a1.y, ctx[5]);
            ctx[6] = fmaf(vv, a1.z, ctx[6]); ctx[7] = fmaf(vv, a1.w, ctx[7]);
        }
    }
}

__global__ __launch_bounds__(256, 2)
void axial_attn_kernel(const float* __restrict__ z,
                       const float* __restrict__ Wq,
                       const float* __restrict__ Wk,
                       float* __restrict__ out)
{
    // LDS: uni aliases {transposed weights (2*64*WST=8704 fl)} and {half-scores 64*SST=8448 fl}
    __shared__ __align__(16) float uni[2 * 64 * WST];
    __shared__ __align__(16) float sA[32 * WST];
    __shared__ __align__(16) float sQ[2048];
    __shared__ __align__(16) float sV[2048];

    const int tid = threadIdx.x;
    const int N  = blockIdx.x;
    const int nb = N >> 2, q = N & 3;
    const int bi = nb >> 7, xi = nb & 127;     // xi = h (branch1) = w (branch2)
    const size_t zbase = (size_t)bi << 20;     // bi * 64*128*128

    // ---- weights (transposed) + A1 tile ----
    stage_weights(Wq, Wk, uni, tid);
    {   // A1[ls][ch] = z[bi, ch, xi, q*32+ls]  (contiguous in ls)
        const float* src = z + zbase + ((size_t)xi << 7) + (q << 5);
        #pragma unroll
        for (int i = tid; i < 2048; i += 256) {
            const int ch = i >> 5, ls = i & 31;
            sA[ls * WST + ch] = src[((size_t)ch << 14) + ls];
        }
    }
    __syncthreads();
    gemm_32x64(sA, uni, sQ, tid);              // Q1
    __syncthreads();

    {   // V input: contiguous 2048-float chunk zflat[N*2048 ..], 32 rows x 64 cols
        const float4* src = (const float4*)(z + ((size_t)N << 11));
        #pragma unroll
        for (int i = tid; i < 512; i += 256) {
            const float4 vv = src[i];
            const int ls = i >> 4, c4 = (i & 15) << 2;   // 16 float4s per 64-float row
            *(float4*)(sA + ls * WST + c4) = vv;
        }
    }
    __syncthreads();
    gemm_32x64(sA, uni + 64 * WST, sV, tid);   // V
    __syncthreads();

    float c1[8], c2[8];
    branch_ctx(sQ, sV, uni, c1, tid);          // branch 1 (destroys weights in uni)
    __syncthreads();

    // ---- restore weights, stage A2, Q2 ----
    stage_weights(Wq, Wk, uni, tid);
    {   // A2[ls][ch] = z[bi, ch, q*32+ls, xi]  (fully strided gather)
        #pragma unroll
        for (int i = tid; i < 2048; i += 256) {
            const int ch = i >> 5, ls = i & 31;
            sA[ls * WST + ch] = z[zbase + ((size_t)ch << 14) + ((size_t)(q * 32 + ls) << 7) + xi];
        }
    }
    __syncthreads();
    gemm_32x64(sA, uni, sQ, tid);              // Q2
    __syncthreads();

    branch_ctx(sQ, sV, uni, c2, tid);          // branch 2

    // ---- epilogue: leaky + add, coalesced float4 stores ----
    const int cd = tid >> 4, ct0 = (tid & 15) * 8;
    float* op = out + ((size_t)N << 11) + cd * 128 + ct0;
    float4 o0, o1;
    o0.x = lrelu(c1[0]) + lrelu(c2[0]); o0.y = lrelu(c1[1]) + lrelu(c2[1]);
    o0.z = lrelu(c1[2]) + lrelu(c2[2]); o0.w = lrelu(c1[3]) + lrelu(c2[3]);
    o1.x = lrelu(c1[4]) + lrelu(c2[4]); o1.y = lrelu(c1[5]) + lrelu(c2[5]);
    o1.z = lrelu(c1[6]) + lrelu(c2[6]); o1.w = lrelu(c1[7]) + lrelu(c2[7]);
    *(float4*)op       = o0;
    *(float4*)(op + 4) = o1;
}

extern "C" void kernel_launch(void* const* d_in, const int* in_sizes, int n_in,
                              void* d_out, int out_size, void* d_ws, size_t ws_size,
                              hipStream_t stream) {
    const float* z  = (const float*)d_in[0];
    const float* Wq = (const float*)d_in[1];
    const float* Wk = (const float*)d_in[2];
    float* out = (float*)d_out;
    hipLaunchKernelGGL(axial_attn_kernel, dim3(4096), dim3(256), 0, stream,
                       z, Wq, Wk, out);
}

// Round 3
// 197.084 us; speedup vs baseline: 2.0228x; 2.0228x over previous
//
#include <hip/hip_runtime.h>

// Fused axial dual-branch attention via bf16 split-precision MFMA. One block per N.
// Per N (32x64 tile): Q = A@Wq^T, V = Vin@Wk^T (reinterp 16x128 via d=l>>1, s=64*(l&1)+o),
// S = 0.25*Q_r^T Q_r, P = softmax_rows(S), ctx = V_r @ P, out = lrelu(ctx1)+lrelu(ctx2).
// All matmuls on v_mfma_f32_16x16x32_bf16 with x = hi+lo bf16 split (3-term / K-packed).
// Verified frag conventions: A[m=lane&15][k=quad*8+j]; B[k=quad*8+j][n=lane&15];
// D row=(lane>>4)*4+reg, col=lane&15.

typedef __attribute__((ext_vector_type(8))) short bh8;
typedef __attribute__((ext_vector_type(4))) float f32x4;
typedef unsigned short u16;
typedef unsigned int u32;

#define MFMA16(a,b,c) __builtin_amdgcn_mfma_f32_16x16x32_bf16(a,b,c,0,0,0)

#define AIMG_ST 72   // u16 units (144B rows, 16B-aligned, bank-spread)
#define QP_ST   40   // Qpack row: [Qh d0..15][Ql d0..15][pad8] (80B)
#define V_ST    136  // V image rows d x 128 s (+8 pad), 272B
#define PT_ST   72   // P^T half-image: 128 t-rows x 64 s-cols (+8 pad), 144B

// LDS byte offsets: PT aliases the transient A-staging images (disjoint lifetimes).
#define OFF_AH   0        // 32*72*2   = 4608
#define OFF_AL   4608     //            4608
#define OFF_PT   0        // 128*72*2  = 18432
#define OFF_QP   18432    // 128*40*2  = 10240
#define OFF_VH   28672    // 16*136*2  = 4352
#define OFF_VL   33024    //            4352
#define LDS_TOT  37376

__device__ __forceinline__ u16 f2bf(float f) {
    u32 u = __float_as_uint(f);
    return (u16)((u + 0x7FFFu + ((u >> 16) & 1u)) >> 16);   // RN-even bf16
}
__device__ __forceinline__ float bf2f(u16 b) { return __uint_as_float(((u32)b) << 16); }
__device__ __forceinline__ void splitbf(float f, u16& h, u16& l) {
    h = f2bf(f);
    l = f2bf(f - bf2f(h));
}
__device__ __forceinline__ float lrelu(float x) { return x > 0.f ? x : 0.2f * x; }

// 32x64 input GEMM, 2 tiles per wave (mi=w>>1, ni in {2*(w&1),+1}), 3-term hi/lo split.
// MODE 0: write Qpack[s][d(hi)/16+d(lo)]; MODE 1: write Vh/Vl[d][s].
template<int MODE>
__device__ __forceinline__ void gemm_in(const u16* Ah, const u16* Al,
                                        const bh8 wh[2][2], const bh8 wl[2][2],
                                        u16* o0, u16* o1,
                                        int miQ, int niA, int lid, int quad)
{
    bh8 ah[2], al[2];
    #pragma unroll
    for (int ks = 0; ks < 2; ++ks) {
        const int off = (miQ*16 + lid)*AIMG_ST + ks*32 + quad*8;
        ah[ks] = *(const bh8*)(Ah + off);
        al[ks] = *(const bh8*)(Al + off);
    }
    #pragma unroll
    for (int ni2 = 0; ni2 < 2; ++ni2) {
        f32x4 acc = {0.f, 0.f, 0.f, 0.f};
        #pragma unroll
        for (int ks = 0; ks < 2; ++ks) {
            acc = MFMA16(ah[ks], wh[ni2][ks], acc);
            acc = MFMA16(ah[ks], wl[ni2][ks], acc);
            acc = MFMA16(al[ks], wh[ni2][ks], acc);
        }
        #pragma unroll
        for (int r = 0; r < 4; ++r) {
            const int l = miQ*16 + quad*4 + r;
            const int o = (niA + ni2)*16 + lid;
            const int d = l >> 1, s = ((l & 1) << 6) + o;   // flat (16,128) reinterp
            u16 h, lo; splitbf(acc[r], h, lo);
            if (MODE == 0) { o0[s*QP_ST + d] = h; o0[s*QP_ST + 16 + d] = lo; }
            else           { o0[d*V_ST + s] = h; o1[d*V_ST + s] = lo; }
        }
    }
}

// One branch: Gram (K=32 packed, 2 mfma/tile) -> register softmax (shfl over 16 lanes)
// -> P^T half-image -> ctx^T accumulation (ctx^T = P^T V^T). Wave w owns s-block
// si=4*round+w (gram) and t-tiles {2w,2w+1} (ctx).
__device__ __forceinline__ void branch_attn(const u16* Qp, const u16* Vh, const u16* Vl,
                                            u16* PT, f32x4& cacc0, f32x4& cacc1,
                                            int w, int lid, int quad)
{
    const f32x4 z4 = {0.f, 0.f, 0.f, 0.f};
    cacc0 = z4; cacc1 = z4;
    for (int round = 0; round < 2; ++round) {
        const int rowS = (round*4 + w)*16 + lid;
        const u16* arow = Qp + rowS*QP_ST;
        bh8 a1 = *(const bh8*)(arow + quad*8);                        // [Qh;Ql]
        bh8 a2 = *(const bh8*)(arow + ((quad >= 2) ? (quad-2)*8 : 0));
        bh8 zzv = a2 ^ a2;
        a2 = (quad < 2) ? zzv : a2;                                   // [0;Qh]
        f32x4 g[8];
        #pragma unroll
        for (int ti = 0; ti < 8; ++ti) {
            const u16* brow = Qp + (ti*16 + lid)*QP_ST;
            bh8 b1 = *(const bh8*)(brow + (quad & 1)*8);              // [Qh;Qh]
            bh8 b2 = *(const bh8*)(brow + quad*8);                    // [Qh;Ql]
            f32x4 acc = z4;
            acc = MFMA16(a1, b1, acc);    // QhᵀQh + QlᵀQh
            acc = MFMA16(a2, b2, acc);    // QhᵀQl
            g[ti] = acc;
        }
        // row softmax: row s fixed per (quad,reg); t spans 8 tiles x 16 lanes of the quad
        float mx[4], sm[4];
        #pragma unroll
        for (int r = 0; r < 4; ++r) {
            float m = g[0][r];
            #pragma unroll
            for (int ti = 1; ti < 8; ++ti) m = fmaxf(m, g[ti][r]);
            m = fmaxf(m, __shfl_xor(m, 1)); m = fmaxf(m, __shfl_xor(m, 2));
            m = fmaxf(m, __shfl_xor(m, 4)); m = fmaxf(m, __shfl_xor(m, 8));
            mx[r] = m; sm[r] = 0.f;
        }
        #pragma unroll
        for (int ti = 0; ti < 8; ++ti)
        #pragma unroll
        for (int r = 0; r < 4; ++r) {
            float p = __expf(0.25f*(g[ti][r] - mx[r]));
            g[ti][r] = p; sm[r] += p;
        }
        #pragma unroll
        for (int r = 0; r < 4; ++r) {
            float ss = sm[r];
            ss += __shfl_xor(ss, 1); ss += __shfl_xor(ss, 2);
            ss += __shfl_xor(ss, 4); ss += __shfl_xor(ss, 8);
            sm[r] = 1.0f / ss;
        }
        #pragma unroll
        for (int ti = 0; ti < 8; ++ti) {   // P^T[t][s_local]: 4 consecutive s per lane
            u32 w0 = (u32)f2bf(g[ti][0]*sm[0]) | ((u32)f2bf(g[ti][1]*sm[1]) << 16);
            u32 w1 = (u32)f2bf(g[ti][2]*sm[2]) | ((u32)f2bf(g[ti][3]*sm[3]) << 16);
            u32* dst = (u32*)(PT + (ti*16 + lid)*PT_ST + w*16 + quad*4);
            dst[0] = w0; dst[1] = w1;
        }
        __syncthreads();
        // ctx^T partial: A = P^T (m=t,k=s_local), B = V^T (k=s,n=d), V split 2-term
        #pragma unroll
        for (int tj2 = 0; tj2 < 2; ++tj2) {
            const int tj = 2*w + tj2;
            f32x4 acc = tj2 ? cacc1 : cacc0;
            #pragma unroll
            for (int ks = 0; ks < 2; ++ks) {
                bh8 pa = *(const bh8*)(PT + (tj*16 + lid)*PT_ST + ks*32 + quad*8);
                const int vo = lid*V_ST + round*64 + ks*32 + quad*8;
                bh8 vh8 = *(const bh8*)(Vh + vo);
                bh8 vl8 = *(const bh8*)(Vl + vo);
                acc = MFMA16(pa, vh8, acc);
                acc = MFMA16(pa, vl8, acc);
            }
            if (tj2) cacc1 = acc; else cacc0 = acc;
        }
        __syncthreads();   // protect PT before next round's writes / later staging
    }
}

__global__ __launch_bounds__(256, 3)
void axial_attn_mfma(const float* __restrict__ z, const float* __restrict__ Wq,
                     const float* __restrict__ Wk, float* __restrict__ out)
{
    __shared__ __align__(16) unsigned char lds[LDS_TOT];
    u16* const ptAh = (u16*)(lds + OFF_AH);
    u16* const ptAl = (u16*)(lds + OFF_AL);
    u16* const ptPT = (u16*)(lds + OFF_PT);
    u16* const ptQP = (u16*)(lds + OFF_QP);
    u16* const ptVH = (u16*)(lds + OFF_VH);
    u16* const ptVL = (u16*)(lds + OFF_VL);

    const int tid = threadIdx.x;
    const int w = tid >> 6, lane = tid & 63, quad = lane >> 4, lid = lane & 15;
    const int N = blockIdx.x, nb = N >> 2, q = N & 3;
    const int bi = nb >> 7, xi = nb & 127;
    const size_t zbase = (size_t)bi << 20;

    // ---- weight B-frags (global -> regs, convert once; Wq reused for Q1 & Q2) ----
    const int miQ = w >> 1, niA = (w & 1) * 2;
    bh8 wqh[2][2], wql[2][2], wkh[2][2], wkl[2][2];
    #pragma unroll
    for (int ni2 = 0; ni2 < 2; ++ni2)
    #pragma unroll
    for (int ks = 0; ks < 2; ++ks) {
        const float* pq = Wq + ((niA+ni2)*16 + lid)*64 + ks*32 + quad*8;
        const float* pk = Wk + ((niA+ni2)*16 + lid)*64 + ks*32 + quad*8;
        float4 q0 = *(const float4*)pq, q1 = *(const float4*)(pq + 4);
        float4 k0 = *(const float4*)pk, k1 = *(const float4*)(pk + 4);
        float vq[8] = {q0.x,q0.y,q0.z,q0.w,q1.x,q1.y,q1.z,q1.w};
        float vk[8] = {k0.x,k0.y,k0.z,k0.w,k1.x,k1.y,k1.z,k1.w};
        bh8 qh, qlo, kh, klo;
        #pragma unroll
        for (int j = 0; j < 8; ++j) {
            u16 h, l;
            splitbf(vq[j], h, l); qh[j] = (short)h; qlo[j] = (short)l;
            splitbf(vk[j], h, l); kh[j] = (short)h; klo[j] = (short)l;
        }
        wqh[ni2][ks] = qh; wql[ni2][ks] = qlo;
        wkh[ni2][ks] = kh; wkl[ni2][ks] = klo;
    }

    // ---- stage A1 (bf16 hi/lo), Q1 GEMM -> Qpack ----
    {
        const float* src = z + zbase + ((size_t)xi << 7) + (q << 5);
        #pragma unroll
        for (int i = tid; i < 2048; i += 256) {
            const int ch = i >> 5, l = i & 31;
            u16 h, lo; splitbf(src[((size_t)ch << 14) + l], h, lo);
            ptAh[l*AIMG_ST + ch] = h; ptAl[l*AIMG_ST + ch] = lo;
        }
    }
    __syncthreads();
    gemm_in<0>(ptAh, ptAl, wqh, wql, ptQP, nullptr, miQ, niA, lid, quad);
    __syncthreads();

    // ---- stage Vin (contiguous float4), V GEMM -> Vh/Vl ----
    {
        const float4* src = (const float4*)(z + ((size_t)N << 11));
        #pragma unroll
        for (int i = tid; i < 512; i += 256) {
            float4 vv = src[i];
            const int l = i >> 4, c = (i & 15) << 2;
            u16 h0,l0,h1,l1,h2,l2,h3,l3;
            splitbf(vv.x,h0,l0); splitbf(vv.y,h1,l1);
            splitbf(vv.z,h2,l2); splitbf(vv.w,h3,l3);
            u32* dh = (u32*)(ptAh + l*AIMG_ST + c);
            u32* dl = (u32*)(ptAl + l*AIMG_ST + c);
            dh[0] = (u32)h0 | ((u32)h1 << 16); dh[1] = (u32)h2 | ((u32)h3 << 16);
            dl[0] = (u32)l0 | ((u32)l1 << 16); dl[1] = (u32)l2 | ((u32)l3 << 16);
        }
    }
    __syncthreads();
    gemm_in<1>(ptAh, ptAl, wkh, wkl, ptVH, ptVL, miQ, niA, lid, quad);
    __syncthreads();

    // ---- branch 1 ----
    f32x4 c10, c11;
    branch_attn(ptQP, ptVH, ptVL, ptPT, c10, c11, w, lid, quad);

    // ---- stage A2 (transpose gather), Q2 GEMM -> Qpack (PT/Aimg & Qpack now dead) ----
    {
        #pragma unroll
        for (int i = tid; i < 2048; i += 256) {
            const int ch = i >> 5, l = i & 31;
            u16 h, lo;
            splitbf(z[zbase + ((size_t)ch << 14) + ((size_t)(q*32 + l) << 7) + xi], h, lo);
            ptAh[l*AIMG_ST + ch] = h; ptAl[l*AIMG_ST + ch] = lo;
        }
    }
    __syncthreads();
    gemm_in<0>(ptAh, ptAl, wqh, wql, ptQP, nullptr, miQ, niA, lid, quad);
    __syncthreads();

    // ---- branch 2 ----
    f32x4 c20, c21;
    branch_attn(ptQP, ptVH, ptVL, ptPT, c20, c21, w, lid, quad);

    // ---- epilogue: out[d][t] = lrelu(ctx1^T[t][d]) + lrelu(ctx2^T[t][d]) ----
    float* obase = out + ((size_t)N << 11) + lid*128;
    #pragma unroll
    for (int tj2 = 0; tj2 < 2; ++tj2) {
        f32x4 a = tj2 ? c11 : c10;
        f32x4 b = tj2 ? c21 : c20;
        float4 ov;
        ov.x = lrelu(a[0]) + lrelu(b[0]);
        ov.y = lrelu(a[1]) + lrelu(b[1]);
        ov.z = lrelu(a[2]) + lrelu(b[2]);
        ov.w = lrelu(a[3]) + lrelu(b[3]);
        *(float4*)(obase + (2*w + tj2)*16 + quad*4) = ov;
    }
}

extern "C" void kernel_launch(void* const* d_in, const int* in_sizes, int n_in,
                              void* d_out, int out_size, void* d_ws, size_t ws_size,
                              hipStream_t stream) {
    const float* z  = (const float*)d_in[0];
    const float* Wq = (const float*)d_in[1];
    const float* Wk = (const float*)d_in[2];
    float* out = (float*)d_out;
    hipLaunchKernelGGL(axial_attn_mfma, dim3(4096), dim3(256), 0, stream,
                       z, Wq, Wk, out);
}

// Round 4
// 186.151 us; speedup vs baseline: 2.1416x; 1.0587x over previous
//
#include <hip/hip_runtime.h>

// Fused axial dual-branch attention via bf16 split-precision MFMA. One block per N.
// Per N (32x64 tile): Q = 0.5*(A@Wq^T), V = Vin@Wk^T (reinterp 16x128 via d=l>>1,
// s=64*(l&1)+o), S = Q_r^T Q_r (0.25 folded into Q), P = softmax_rows(S) [no max-sub:
// scores <= ~12 << 88], ctx = V_r @ P, out = lrelu(ctx1)+lrelu(ctx2).
// Split precision: x = hi + lo, hi = trunc-bf16(x), lo = RN-bf16(x-hi) -> rel err 2^-17.
// Weights pre-split by a tiny pre-kernel into d_ws (L2-resident, loaded as b128 frags).
// Frag conventions (HW-verified): A[m=lane&15][k=quad*8+j]; B[k=quad*8+j][n=lane&15];
// D row=(lane>>4)*4+reg, col=lane&15.

typedef __attribute__((ext_vector_type(8))) short bh8;
typedef __attribute__((ext_vector_type(4))) float f32x4;
typedef unsigned short u16;
typedef unsigned int u32;

#define MFMA16(a,b,c) __builtin_amdgcn_mfma_f32_16x16x32_bf16(a,b,c,0,0,0)

#define AIMG_ST 72   // u16 units (144B rows)
#define QP_ST   40   // Qpack row: [Qh d0..15][Ql d0..15][pad8]
#define V_ST    136  // V image rows d x 128 s (+8 pad)
#define PT_ST   72   // P^T half-image: 128 t-rows x 64 s-cols (+8 pad)

#define OFF_AH   0        // 32*72*2   = 4608
#define OFF_AL   4608
#define OFF_PT   0        // 128*72*2  = 18432 (aliases A-staging, disjoint lifetime)
#define OFF_QP   18432    // 128*40*2  = 10240
#define OFF_VH   28672    // 16*136*2  = 4352
#define OFF_VL   33024
#define LDS_TOT  37376

// ---- cheap splits: hi = trunc-bf16 (exact upper 16 bits), lo = RN-bf16(residual) ----
__device__ __forceinline__ void split3(float f, u16& h, u16& l) {
    u32 u = __float_as_uint(f);
    u32 hf = u & 0xFFFF0000u;
    float r = f - __uint_as_float(hf);
    h = (u16)(hf >> 16);
    l = (u16)((__float_as_uint(r) + 0x8000u) >> 16);
}
__device__ __forceinline__ void split2pk(float f0, float f1, u32& hp, u32& lp) {
    u32 u0 = __float_as_uint(f0), u1 = __float_as_uint(f1);
    u32 h0 = u0 & 0xFFFF0000u,  h1 = u1 & 0xFFFF0000u;
    float r0 = f0 - __uint_as_float(h0);
    float r1 = f1 - __uint_as_float(h1);
    hp = (h0 >> 16) | h1;
    lp = ((__float_as_uint(r0) + 0x8000u) >> 16) | ((__float_as_uint(r1) + 0x8000u) & 0xFFFF0000u);
}
__device__ __forceinline__ float lrelu(float x) { return x > 0.f ? x : 0.2f * x; }

// ---- pre-kernel: split Wq,Wk into ws as bf16 hi/lo (same row-major (o,ch) layout) ----
// ws u16 layout: [WqH 4096][WqL 4096][WkH 4096][WkL 4096]
__global__ void split_w_kernel(const float* __restrict__ Wq,
                               const float* __restrict__ Wk,
                               u16* __restrict__ ws)
{
    const int i = blockIdx.x * 256 + threadIdx.x;      // 0..8191
    const int j = i & 4095;
    const float f = (i < 4096) ? Wq[j] : Wk[j];
    const int base = (i < 4096) ? 0 : 8192;
    u16 h, l; split3(f, h, l);
    ws[base + j] = h;
    ws[base + 4096 + j] = l;
}

// 32x64 input GEMM, 2 tiles per wave, 3-term hi/lo split.
// MODE 0: write Qpack[s][d(hi)/16+d(lo)] of 0.5*acc; MODE 1: write Vh/Vl[d][s].
template<int MODE>
__device__ __forceinline__ void gemm_in(const u16* Ah, const u16* Al,
                                        const bh8 wh[2][2], const bh8 wl[2][2],
                                        u16* o0, u16* o1,
                                        int miQ, int niA, int lid, int quad)
{
    bh8 ah[2], al[2];
    #pragma unroll
    for (int ks = 0; ks < 2; ++ks) {
        const int off = (miQ*16 + lid)*AIMG_ST + ks*32 + quad*8;
        ah[ks] = *(const bh8*)(Ah + off);
        al[ks] = *(const bh8*)(Al + off);
    }
    #pragma unroll
    for (int ni2 = 0; ni2 < 2; ++ni2) {
        f32x4 acc = {0.f, 0.f, 0.f, 0.f};
        #pragma unroll
        for (int ks = 0; ks < 2; ++ks) {
            acc = MFMA16(ah[ks], wh[ni2][ks], acc);
            acc = MFMA16(ah[ks], wl[ni2][ks], acc);
            acc = MFMA16(al[ks], wh[ni2][ks], acc);
        }
        #pragma unroll
        for (int r = 0; r < 4; ++r) {
            const int l = miQ*16 + quad*4 + r;
            const int o = (niA + ni2)*16 + lid;
            const int d = l >> 1, s = ((l & 1) << 6) + o;   // flat (16,128) reinterp
            u16 h, lo;
            split3(MODE == 0 ? 0.5f*acc[r] : acc[r], h, lo);
            if (MODE == 0) { o0[s*QP_ST + d] = h; o0[s*QP_ST + 16 + d] = lo; }
            else           { o0[d*V_ST + s] = h; o1[d*V_ST + s] = lo; }
        }
    }
}

// One branch: Gram (K=32 packed, 2 mfma/tile) -> no-max softmax (shfl sum over 16)
// -> P^T half-image -> ctx^T accumulation (ctx^T = P^T V^T).
__device__ __forceinline__ void branch_attn(const u16* Qp, const u16* Vh, const u16* Vl,
                                            u16* PT, f32x4& cacc0, f32x4& cacc1,
                                            int w, int lid, int quad)
{
    const f32x4 z4 = {0.f, 0.f, 0.f, 0.f};
    cacc0 = z4; cacc1 = z4;
    for (int round = 0; round < 2; ++round) {
        const int rowS = (round*4 + w)*16 + lid;
        const u16* arow = Qp + rowS*QP_ST;
        bh8 a1 = *(const bh8*)(arow + quad*8);                        // [Qh;Ql]
        bh8 a2 = *(const bh8*)(arow + ((quad >= 2) ? (quad-2)*8 : 0));
        bh8 zzv = a2 ^ a2;
        a2 = (quad < 2) ? zzv : a2;                                   // [0;Qh]
        f32x4 g[8];
        #pragma unroll
        for (int ti = 0; ti < 8; ++ti) {
            const u16* brow = Qp + (ti*16 + lid)*QP_ST;
            bh8 b1 = *(const bh8*)(brow + (quad & 1)*8);              // [Qh;Qh]
            bh8 b2 = *(const bh8*)(brow + quad*8);                    // [Qh;Ql]
            f32x4 acc = z4;
            acc = MFMA16(a1, b1, acc);    // QhᵀQh + QlᵀQh
            acc = MFMA16(a2, b2, acc);    // QhᵀQl
            g[ti] = acc;
        }
        // ---- softmax over t (scores already 0.25-scaled via Q*0.5; no max-sub) ----
        float sm[4] = {0.f, 0.f, 0.f, 0.f};
        #pragma unroll
        for (int ti = 0; ti < 8; ++ti)
        #pragma unroll
        for (int r = 0; r < 4; ++r) {
            const float p = __expf(g[ti][r]);
            g[ti][r] = p; sm[r] += p;
        }
        #pragma unroll
        for (int r = 0; r < 4; ++r) {
            float ss = sm[r];
            ss += __shfl_xor(ss, 1); ss += __shfl_xor(ss, 2);
            ss += __shfl_xor(ss, 4); ss += __shfl_xor(ss, 8);
            sm[r] = 1.0f / ss;
        }
        #pragma unroll
        for (int ti = 0; ti < 8; ++ti) {   // P^T[t][s]: RN-bf16 pair pack, 4 s per lane
            const u32 r0 = __float_as_uint(g[ti][0]*sm[0]) + 0x8000u;
            const u32 r1 = __float_as_uint(g[ti][1]*sm[1]) + 0x8000u;
            const u32 r2 = __float_as_uint(g[ti][2]*sm[2]) + 0x8000u;
            const u32 r3 = __float_as_uint(g[ti][3]*sm[3]) + 0x8000u;
            u32* dst = (u32*)(PT + (ti*16 + lid)*PT_ST + w*16 + quad*4);
            dst[0] = (r0 >> 16) | (r1 & 0xFFFF0000u);
            dst[1] = (r2 >> 16) | (r3 & 0xFFFF0000u);
        }
        __syncthreads();
        // ---- ctx^T partial: A = P^T (m=t,k=s), B = V^T (k=s,n=d), V 2-term split ----
        #pragma unroll
        for (int tj2 = 0; tj2 < 2; ++tj2) {
            const int tj = 2*w + tj2;
            f32x4 acc = tj2 ? cacc1 : cacc0;
            #pragma unroll
            for (int ks = 0; ks < 2; ++ks) {
                bh8 pa = *(const bh8*)(PT + (tj*16 + lid)*PT_ST + ks*32 + quad*8);
                const int vo = lid*V_ST + round*64 + ks*32 + quad*8;
                bh8 vh8 = *(const bh8*)(Vh + vo);
                bh8 vl8 = *(const bh8*)(Vl + vo);
                acc = MFMA16(pa, vh8, acc);
                acc = MFMA16(pa, vl8, acc);
            }
            if (tj2) cacc1 = acc; else cacc0 = acc;
        }
        __syncthreads();
    }
}

__global__ __launch_bounds__(256, 4)
void axial_attn_mfma(const float* __restrict__ z, const u16* __restrict__ wsu,
                     float* __restrict__ out)
{
    __shared__ __align__(16) unsigned char lds[LDS_TOT];
    u16* const ptAh = (u16*)(lds + OFF_AH);
    u16* const ptAl = (u16*)(lds + OFF_AL);
    u16* const ptPT = (u16*)(lds + OFF_PT);
    u16* const ptQP = (u16*)(lds + OFF_QP);
    u16* const ptVH = (u16*)(lds + OFF_VH);
    u16* const ptVL = (u16*)(lds + OFF_VL);

    const int tid = threadIdx.x;
    const int w = tid >> 6, lane = tid & 63, quad = lane >> 4, lid = lane & 15;
    const int N = blockIdx.x, nb = N >> 2, q = N & 3;
    const int bi = nb >> 7, xi = nb & 127;
    const size_t zbase = (size_t)bi << 20;

    // ---- weight B-frags: direct b128 loads from pre-split ws (L2-hot) ----
    const int miQ = w >> 1, niA = (w & 1) * 2;
    bh8 wqh[2][2], wql[2][2], wkh[2][2], wkl[2][2];
    #pragma unroll
    for (int ni2 = 0; ni2 < 2; ++ni2)
    #pragma unroll
    for (int ks = 0; ks < 2; ++ks) {
        const int off = ((niA + ni2)*16 + lid)*64 + ks*32 + quad*8;
        wqh[ni2][ks] = *(const bh8*)(wsu + off);
        wql[ni2][ks] = *(const bh8*)(wsu + 4096 + off);
        wkh[ni2][ks] = *(const bh8*)(wsu + 8192 + off);
        wkl[ni2][ks] = *(const bh8*)(wsu + 12288 + off);
    }

    // ---- stage A1 (hi/lo), Q1 GEMM -> Qpack ----
    {
        const float* src = z + zbase + ((size_t)xi << 7) + (q << 5);
        #pragma unroll
        for (int i = tid; i < 2048; i += 256) {
            const int ch = i >> 5, l = i & 31;
            u16 h, lo; split3(src[((size_t)ch << 14) + l], h, lo);
            ptAh[l*AIMG_ST + ch] = h; ptAl[l*AIMG_ST + ch] = lo;
        }
    }
    __syncthreads();
    gemm_in<0>(ptAh, ptAl, wqh, wql, ptQP, nullptr, miQ, niA, lid, quad);
    __syncthreads();

    // ---- stage Vin (contiguous float4, pair-packed split), V GEMM -> Vh/Vl ----
    {
        const float4* src = (const float4*)(z + ((size_t)N << 11));
        #pragma unroll
        for (int i = tid; i < 512; i += 256) {
            const float4 vv = src[i];
            const int l = i >> 4, c = (i & 15) << 2;
            u32 hp0, lp0, hp1, lp1;
            split2pk(vv.x, vv.y, hp0, lp0);
            split2pk(vv.z, vv.w, hp1, lp1);
            u32* dh = (u32*)(ptAh + l*AIMG_ST + c);
            u32* dl = (u32*)(ptAl + l*AIMG_ST + c);
            dh[0] = hp0; dh[1] = hp1;
            dl[0] = lp0; dl[1] = lp1;
        }
    }
    __syncthreads();
    gemm_in<1>(ptAh, ptAl, wkh, wkl, ptVH, ptVL, miQ, niA, lid, quad);
    __syncthreads();

    // ---- branch 1 ----
    f32x4 c10, c11;
    branch_attn(ptQP, ptVH, ptVL, ptPT, c10, c11, w, lid, quad);

    // ---- stage A2 (transpose gather), Q2 GEMM -> Qpack ----
    {
        #pragma unroll
        for (int i = tid; i < 2048; i += 256) {
            const int ch = i >> 5, l = i & 31;
            u16 h, lo;
            split3(z[zbase + ((size_t)ch << 14) + ((size_t)(q*32 + l) << 7) + xi], h, lo);
            ptAh[l*AIMG_ST + ch] = h; ptAl[l*AIMG_ST + ch] = lo;
        }
    }
    __syncthreads();
    gemm_in<0>(ptAh, ptAl, wqh, wql, ptQP, nullptr, miQ, niA, lid, quad);
    __syncthreads();

    // ---- branch 2 ----
    f32x4 c20, c21;
    branch_attn(ptQP, ptVH, ptVL, ptPT, c20, c21, w, lid, quad);

    // ---- epilogue ----
    float* obase = out + ((size_t)N << 11) + lid*128;
    #pragma unroll
    for (int tj2 = 0; tj2 < 2; ++tj2) {
        f32x4 a = tj2 ? c11 : c10;
        f32x4 b = tj2 ? c21 : c20;
        float4 ov;
        ov.x = lrelu(a[0]) + lrelu(b[0]);
        ov.y = lrelu(a[1]) + lrelu(b[1]);
        ov.z = lrelu(a[2]) + lrelu(b[2]);
        ov.w = lrelu(a[3]) + lrelu(b[3]);
        *(float4*)(obase + (2*w + tj2)*16 + quad*4) = ov;
    }
}

extern "C" void kernel_launch(void* const* d_in, const int* in_sizes, int n_in,
                              void* d_out, int out_size, void* d_ws, size_t ws_size,
                              hipStream_t stream) {
    const float* z  = (const float*)d_in[0];
    const float* Wq = (const float*)d_in[1];
    const float* Wk = (const float*)d_in[2];
    float* out = (float*)d_out;
    u16* ws = (u16*)d_ws;
    hipLaunchKernelGGL(split_w_kernel, dim3(32), dim3(256), 0, stream, Wq, Wk, ws);
    hipLaunchKernelGGL(axial_attn_mfma, dim3(4096), dim3(256), 0, stream, z, ws, out);
}

// Round 5
// 161.143 us; speedup vs baseline: 2.4740x; 1.1552x over previous
//
#include <hip/hip_runtime.h>

// Fused axial dual-branch attention via bf16 split-precision MFMA. One block per N.
// R5: register prefetch of all z reads (A1/V/A2) at kernel top + XCD-aware block
// swizzle (same-XCD blocks cover contiguous xi -> A2 cache-line reuse inside one L2).
// Per N (32x64 tile): Q = 0.5*(A@Wq^T), V = Vin@Wk^T, S = Q_r^T Q_r, P = softmax rows
// (no max-sub: |scores|<=~12), ctx = V_r @ P, out = lrelu(ctx1)+lrelu(ctx2).
// Split: x = hi + lo, hi = trunc-bf16, lo = RN-bf16(residual) -> rel err ~2^-17.
// Frags (HW-verified): A[m=lane&15][k=quad*8+j]; B[k=quad*8+j][n=lane&15];
// D row=(lane>>4)*4+reg, col=lane&15.

typedef __attribute__((ext_vector_type(8))) short bh8;
typedef __attribute__((ext_vector_type(4))) float f32x4;
typedef unsigned short u16;
typedef unsigned int u32;

#define MFMA16(a,b,c) __builtin_amdgcn_mfma_f32_16x16x32_bf16(a,b,c,0,0,0)

#define AIMG_ST 72
#define QP_ST   40
#define V_ST    136
#define PT_ST   72

#define OFF_AH   0
#define OFF_AL   4608
#define OFF_PT   0
#define OFF_QP   18432
#define OFF_VH   28672
#define OFF_VL   33024
#define LDS_TOT  37376

__device__ __forceinline__ void split3(float f, u16& h, u16& l) {
    u32 u = __float_as_uint(f);
    u32 hf = u & 0xFFFF0000u;
    float r = f - __uint_as_float(hf);
    h = (u16)(hf >> 16);
    l = (u16)((__float_as_uint(r) + 0x8000u) >> 16);
}
__device__ __forceinline__ void split2pk(float f0, float f1, u32& hp, u32& lp) {
    u32 u0 = __float_as_uint(f0), u1 = __float_as_uint(f1);
    u32 h0 = u0 & 0xFFFF0000u,  h1 = u1 & 0xFFFF0000u;
    float r0 = f0 - __uint_as_float(h0);
    float r1 = f1 - __uint_as_float(h1);
    hp = (h0 >> 16) | h1;
    lp = ((__float_as_uint(r0) + 0x8000u) >> 16) | ((__float_as_uint(r1) + 0x8000u) & 0xFFFF0000u);
}
__device__ __forceinline__ float lrelu(float x) { return x > 0.f ? x : 0.2f * x; }

// ws u16 layout: [WqH 4096][WqL 4096][WkH 4096][WkL 4096]
__global__ void split_w_kernel(const float* __restrict__ Wq,
                               const float* __restrict__ Wk,
                               u16* __restrict__ ws)
{
    const int i = blockIdx.x * 256 + threadIdx.x;      // 0..8191
    const int j = i & 4095;
    const float f = (i < 4096) ? Wq[j] : Wk[j];
    const int base = (i < 4096) ? 0 : 8192;
    u16 h, l; split3(f, h, l);
    ws[base + j] = h;
    ws[base + 4096 + j] = l;
}

// 32x64 input GEMM, 2 n-tiles per wave, 3-term hi/lo split. Weights passed BY VALUE
// (8 bh8) so they live in VGPRs, never memory. MODE 0: Qpack of 0.5*acc; MODE 1: Vh/Vl.
template<int MODE>
__device__ __forceinline__ void gemm_in(const u16* Ah, const u16* Al,
                                        bh8 h0a, bh8 h0b, bh8 l0a, bh8 l0b,
                                        bh8 h1a, bh8 h1b, bh8 l1a, bh8 l1b,
                                        u16* o0, u16* o1,
                                        int miQ, int niA, int lid, int quad)
{
    const int offA = (miQ*16 + lid)*AIMG_ST + quad*8;
    bh8 ah0 = *(const bh8*)(Ah + offA);
    bh8 ah1 = *(const bh8*)(Ah + offA + 32);
    bh8 al0 = *(const bh8*)(Al + offA);
    bh8 al1 = *(const bh8*)(Al + offA + 32);
    f32x4 acc0 = {0.f,0.f,0.f,0.f}, acc1 = {0.f,0.f,0.f,0.f};
    acc0 = MFMA16(ah0, h0a, acc0); acc0 = MFMA16(ah0, l0a, acc0); acc0 = MFMA16(al0, h0a, acc0);
    acc0 = MFMA16(ah1, h0b, acc0); acc0 = MFMA16(ah1, l0b, acc0); acc0 = MFMA16(al1, h0b, acc0);
    acc1 = MFMA16(ah0, h1a, acc1); acc1 = MFMA16(ah0, l1a, acc1); acc1 = MFMA16(al0, h1a, acc1);
    acc1 = MFMA16(ah1, h1b, acc1); acc1 = MFMA16(ah1, l1b, acc1); acc1 = MFMA16(al1, h1b, acc1);
    #pragma unroll
    for (int r = 0; r < 4; ++r) {
        const int l = miQ*16 + quad*4 + r;
        const int d = l >> 1;
        const int sbase = (l & 1) << 6;
        {
            const int s = sbase + (niA + 0)*16 + lid;
            u16 h, lo; split3(MODE == 0 ? 0.5f*acc0[r] : acc0[r], h, lo);
            if (MODE == 0) { o0[s*QP_ST + d] = h; o0[s*QP_ST + 16 + d] = lo; }
            else           { o0[d*V_ST + s] = h; o1[d*V_ST + s] = lo; }
        }
        {
            const int s = sbase + (niA + 1)*16 + lid;
            u16 h, lo; split3(MODE == 0 ? 0.5f*acc1[r] : acc1[r], h, lo);
            if (MODE == 0) { o0[s*QP_ST + d] = h; o0[s*QP_ST + 16 + d] = lo; }
            else           { o0[d*V_ST + s] = h; o1[d*V_ST + s] = lo; }
        }
    }
}

// One branch: Gram (K=32 packed, 2 mfma/tile) -> no-max softmax -> P^T -> ctx^T.
__device__ __forceinline__ void branch_attn(const u16* Qp, const u16* Vh, const u16* Vl,
                                            u16* PT, f32x4& cacc0, f32x4& cacc1,
                                            int w, int lid, int quad)
{
    const f32x4 z4 = {0.f, 0.f, 0.f, 0.f};
    cacc0 = z4; cacc1 = z4;
    for (int round = 0; round < 2; ++round) {
        const int rowS = (round*4 + w)*16 + lid;
        const u16* arow = Qp + rowS*QP_ST;
        bh8 a1 = *(const bh8*)(arow + quad*8);                        // [Qh;Ql]
        bh8 a2 = *(const bh8*)(arow + ((quad >= 2) ? (quad-2)*8 : 0));
        bh8 zzv = a2 ^ a2;
        a2 = (quad < 2) ? zzv : a2;                                   // [0;Qh]
        f32x4 g[8];
        #pragma unroll
        for (int ti = 0; ti < 8; ++ti) {
            const u16* brow = Qp + (ti*16 + lid)*QP_ST;
            bh8 b1 = *(const bh8*)(brow + (quad & 1)*8);              // [Qh;Qh]
            bh8 b2 = *(const bh8*)(brow + quad*8);                    // [Qh;Ql]
            f32x4 acc = z4;
            acc = MFMA16(a1, b1, acc);
            acc = MFMA16(a2, b2, acc);
            g[ti] = acc;
        }
        float sm[4] = {0.f, 0.f, 0.f, 0.f};
        #pragma unroll
        for (int ti = 0; ti < 8; ++ti)
        #pragma unroll
        for (int r = 0; r < 4; ++r) {
            const float p = __expf(g[ti][r]);
            g[ti][r] = p; sm[r] += p;
        }
        #pragma unroll
        for (int r = 0; r < 4; ++r) {
            float ss = sm[r];
            ss += __shfl_xor(ss, 1); ss += __shfl_xor(ss, 2);
            ss += __shfl_xor(ss, 4); ss += __shfl_xor(ss, 8);
            sm[r] = 1.0f / ss;
        }
        #pragma unroll
        for (int ti = 0; ti < 8; ++ti) {
            const u32 r0 = __float_as_uint(g[ti][0]*sm[0]) + 0x8000u;
            const u32 r1 = __float_as_uint(g[ti][1]*sm[1]) + 0x8000u;
            const u32 r2 = __float_as_uint(g[ti][2]*sm[2]) + 0x8000u;
            const u32 r3 = __float_as_uint(g[ti][3]*sm[3]) + 0x8000u;
            u32* dst = (u32*)(PT + (ti*16 + lid)*PT_ST + w*16 + quad*4);
            dst[0] = (r0 >> 16) | (r1 & 0xFFFF0000u);
            dst[1] = (r2 >> 16) | (r3 & 0xFFFF0000u);
        }
        __syncthreads();
        #pragma unroll
        for (int tj2 = 0; tj2 < 2; ++tj2) {
            const int tj = 2*w + tj2;
            f32x4 acc = tj2 ? cacc1 : cacc0;
            #pragma unroll
            for (int ks = 0; ks < 2; ++ks) {
                bh8 pa = *(const bh8*)(PT + (tj*16 + lid)*PT_ST + ks*32 + quad*8);
                const int vo = lid*V_ST + round*64 + ks*32 + quad*8;
                bh8 vh8 = *(const bh8*)(Vh + vo);
                bh8 vl8 = *(const bh8*)(Vl + vo);
                acc = MFMA16(pa, vh8, acc);
                acc = MFMA16(pa, vl8, acc);
            }
            if (tj2) cacc1 = acc; else cacc0 = acc;
        }
        __syncthreads();
    }
}

#define WOFF(n, ks) (((n)*16 + lid)*64 + (ks)*32 + quad*8)

__global__ __launch_bounds__(256, 4)
void axial_attn_mfma(const float* __restrict__ z, const u16* __restrict__ wsu,
                     float* __restrict__ out)
{
    __shared__ __align__(16) unsigned char lds[LDS_TOT];
    u16* const ptAh = (u16*)(lds + OFF_AH);
    u16* const ptAl = (u16*)(lds + OFF_AL);
    u16* const ptPT = (u16*)(lds + OFF_PT);
    u16* const ptQP = (u16*)(lds + OFF_QP);
    u16* const ptVH = (u16*)(lds + OFF_VH);
    u16* const ptVL = (u16*)(lds + OFF_VL);

    const int tid = threadIdx.x;
    const int w = tid >> 6, lane = tid & 63, quad = lane >> 4, lid = lane & 15;

    // ---- XCD-aware swizzle: same-XCD blocks (blk%8 equal) cover contiguous xi ----
    const int blk = blockIdx.x;
    const int j   = blk >> 3;
    const int xi  = ((blk & 7) << 4) | (j & 15);
    const int q   = (j >> 4) & 3;
    const int bi  = j >> 6;
    const int N   = (((bi << 7) | xi) << 2) | q;
    const size_t zbase = (size_t)bi << 20;

    const int ch0 = tid >> 5, l5 = tid & 31;       // A1/A2 decomposition
    const int vl0 = tid >> 4, vc0 = (tid & 15) << 2;

    // ---- register prefetch of ALL z reads (latency rides under compute) ----
    float a1r[8], a2r[8];
    float4 v4[2];
    {
        const float* s1 = z + zbase + ((size_t)xi << 7) + (q << 5) + l5;
        const float* s2 = z + zbase + (((size_t)(q*32 + l5)) << 7) + xi;
        #pragma unroll
        for (int k = 0; k < 8; ++k)
            a1r[k] = s1[(size_t)(ch0 + 8*k) << 14];
        const float4* sv = (const float4*)(z + ((size_t)N << 11));
        v4[0] = sv[tid]; v4[1] = sv[tid + 256];
        #pragma unroll
        for (int k = 0; k < 8; ++k)
            a2r[k] = s2[(size_t)(ch0 + 8*k) << 14];
    }

    // ---- Wq B-frags (L2-hot ws, kept in VGPRs through both Q gemms) ----
    const int niA = (w & 1) * 2, miQ = w >> 1;
    const bh8 qh0a = *(const bh8*)(wsu +        WOFF(niA+0,0));
    const bh8 qh0b = *(const bh8*)(wsu +        WOFF(niA+0,1));
    const bh8 qh1a = *(const bh8*)(wsu +        WOFF(niA+1,0));
    const bh8 qh1b = *(const bh8*)(wsu +        WOFF(niA+1,1));
    const bh8 ql0a = *(const bh8*)(wsu + 4096 + WOFF(niA+0,0));
    const bh8 ql0b = *(const bh8*)(wsu + 4096 + WOFF(niA+0,1));
    const bh8 ql1a = *(const bh8*)(wsu + 4096 + WOFF(niA+1,0));
    const bh8 ql1b = *(const bh8*)(wsu + 4096 + WOFF(niA+1,1));

    // ---- stage A1 from regs, Q1 ----
    #pragma unroll
    for (int k = 0; k < 8; ++k) {
        u16 h, lo; split3(a1r[k], h, lo);
        ptAh[l5*AIMG_ST + ch0 + 8*k] = h;
        ptAl[l5*AIMG_ST + ch0 + 8*k] = lo;
    }
    __syncthreads();
    gemm_in<0>(ptAh, ptAl, qh0a, qh0b, ql0a, ql0b, qh1a, qh1b, ql1a, ql1b,
               ptQP, nullptr, miQ, niA, lid, quad);
    __syncthreads();

    // ---- Wk frags (scoped: die after V gemm), stage V from regs, V gemm ----
    {
        const bh8 kh0a = *(const bh8*)(wsu +  8192 + WOFF(niA+0,0));
        const bh8 kh0b = *(const bh8*)(wsu +  8192 + WOFF(niA+0,1));
        const bh8 kh1a = *(const bh8*)(wsu +  8192 + WOFF(niA+1,0));
        const bh8 kh1b = *(const bh8*)(wsu +  8192 + WOFF(niA+1,1));
        const bh8 kl0a = *(const bh8*)(wsu + 12288 + WOFF(niA+0,0));
        const bh8 kl0b = *(const bh8*)(wsu + 12288 + WOFF(niA+0,1));
        const bh8 kl1a = *(const bh8*)(wsu + 12288 + WOFF(niA+1,0));
        const bh8 kl1b = *(const bh8*)(wsu + 12288 + WOFF(niA+1,1));
        #pragma unroll
        for (int k = 0; k < 2; ++k) {
            const float4 vv = v4[k];
            u32 hp0, lp0, hp1, lp1;
            split2pk(vv.x, vv.y, hp0, lp0);
            split2pk(vv.z, vv.w, hp1, lp1);
            u32* dh = (u32*)(ptAh + (vl0 + 16*k)*AIMG_ST + vc0);
            u32* dl = (u32*)(ptAl + (vl0 + 16*k)*AIMG_ST + vc0);
            dh[0] = hp0; dh[1] = hp1;
            dl[0] = lp0; dl[1] = lp1;
        }
        __syncthreads();
        gemm_in<1>(ptAh, ptAl, kh0a, kh0b, kl0a, kl0b, kh1a, kh1b, kl1a, kl1b,
                   ptVH, ptVL, miQ, niA, lid, quad);
    }
    __syncthreads();

    // ---- branch 1 (a2r rides in registers through this) ----
    f32x4 c10, c11;
    branch_attn(ptQP, ptVH, ptVL, ptPT, c10, c11, w, lid, quad);

    // ---- stage A2 from regs (PT/A region free), Q2 ----
    #pragma unroll
    for (int k = 0; k < 8; ++k) {
        u16 h, lo; split3(a2r[k], h, lo);
        ptAh[l5*AIMG_ST + ch0 + 8*k] = h;
        ptAl[l5*AIMG_ST + ch0 + 8*k] = lo;
    }
    __syncthreads();
    gemm_in<0>(ptAh, ptAl, qh0a, qh0b, ql0a, ql0b, qh1a, qh1b, ql1a, ql1b,
               ptQP, nullptr, miQ, niA, lid, quad);
    __syncthreads();

    // ---- branch 2 ----
    f32x4 c20, c21;
    branch_attn(ptQP, ptVH, ptVL, ptPT, c20, c21, w, lid, quad);

    // ---- epilogue ----
    float* obase = out + ((size_t)N << 11) + lid*128;
    #pragma unroll
    for (int tj2 = 0; tj2 < 2; ++tj2) {
        f32x4 a = tj2 ? c11 : c10;
        f32x4 b = tj2 ? c21 : c20;
        float4 ov;
        ov.x = lrelu(a[0]) + lrelu(b[0]);
        ov.y = lrelu(a[1]) + lrelu(b[1]);
        ov.z = lrelu(a[2]) + lrelu(b[2]);
        ov.w = lrelu(a[3]) + lrelu(b[3]);
        *(float4*)(obase + (2*w + tj2)*16 + quad*4) = ov;
    }
}

extern "C" void kernel_launch(void* const* d_in, const int* in_sizes, int n_in,
                              void* d_out, int out_size, void* d_ws, size_t ws_size,
                              hipStream_t stream) {
    const float* z  = (const float*)d_in[0];
    const float* Wq = (const float*)d_in[1];
    const float* Wk = (const float*)d_in[2];
    float* out = (float*)d_out;
    u16* ws = (u16*)d_ws;
    hipLaunchKernelGGL(split_w_kernel, dim3(32), dim3(256), 0, stream, Wq, Wk, ws);
    hipLaunchKernelGGL(axial_attn_mfma, dim3(4096), dim3(256), 0, stream, z, ws, out);
}